// Round 1
// baseline (1051.479 us; speedup 1.0000x reference)
//
#include <hip/hip_runtime.h>
#include <math.h>

constexpr int CIN      = 256;
constexpr int HW       = 16384;      // 128*128
constexpr int NMID     = 64;
constexpr int KCH      = 16;         // K-chunk staged per iteration
constexpr int HWTILE   = 64;         // spatial positions per block
constexpr int NORM_OFF = 512;                       // mask (8*64) floats first
constexpr int K_OFF    = 75497984;   // 512 + 8*64*9*16384
constexpr int IDX_OFF  = 75497985;

// ---------------------------------------------------------------------------
// Zero the mask region of d_out; it doubles as the score-sum accumulator.
__global__ __launch_bounds__(512) void zero_mask_kernel(float* __restrict__ out) {
    out[threadIdx.x] = 0.0f;
}

// ---------------------------------------------------------------------------
// Fused GEMM (640x256 @ 256xHW) + per-position 9-way softmax + score partial sums.
// Block: 512 threads. Each block handles ALL 64 mids for 64 spatial positions of
// one batch, so x is read exactly once from HBM.
// Thread (mid_t = tid>>3 in [0,64), hw_t = tid&7 in [0,8)):
//   10 outputs (1 score + 9 kernel taps) x 8 consecutive positions = 80 accs.
__global__ __launch_bounds__(512) void fused_main(const float* __restrict__ x,
                                                  const float* __restrict__ Wm,
                                                  const float* __restrict__ bvec,
                                                  float* __restrict__ out)
{
    __shared__ float xs[KCH * HWTILE];       // 4 KB,  [c][hw]
    __shared__ float wsl[KCH * NMID * 12];   // 48 KB, [c][mid*12 + j] (j<10 used)
    const int tid    = threadIdx.x;
    const int bid    = blockIdx.x;
    const int hw_blk = bid & 255;
    const int b      = bid >> 8;
    const int hw0    = hw_blk * HWTILE;
    const int mid_t  = tid >> 3;
    const int hw_t   = tid & 7;

    float acc[10][8];
    #pragma unroll
    for (int j = 0; j < 10; ++j)
        #pragma unroll
        for (int p = 0; p < 8; ++p) acc[j][p] = 0.0f;

    const float* xb = x + (size_t)b * CIN * HW + hw0;

    #pragma unroll 1
    for (int ch = 0; ch < CIN / KCH; ++ch) {
        const int c0 = ch * KCH;
        // ---- stage x chunk: 16 rows x 64 floats (coalesced float4) ----
        if (tid < 256) {
            const int c = tid >> 4, f = tid & 15;
            *(float4*)&xs[c * HWTILE + f * 4] =
                *(const float4*)(xb + (size_t)(c0 + c) * HW + f * 4);
        }
        // ---- stage W chunk, repacked [c][mid*12+j]; j=0 is score row ----
        #pragma unroll 1
        for (int i = tid; i < KCH * NMID * 10; i += 512) {
            const int cc  = i & 15;
            const int r   = i >> 4;            // 0..639
            const int mid = r / 10;
            const int j   = r - mid * 10;
            const int o   = (j == 0) ? mid : (NMID + mid * 9 + (j - 1));
            wsl[cc * (NMID * 12) + mid * 12 + j] = Wm[(size_t)o * CIN + c0 + cc];
        }
        __syncthreads();
        // ---- FMA inner loop: per c: 5 ds_read_b128 + 80 v_fma_f32 ----
        #pragma unroll 4
        for (int c = 0; c < KCH; ++c) {
            const float4 xv0 = *(const float4*)&xs[c * HWTILE + hw_t * 8];
            const float4 xv1 = *(const float4*)&xs[c * HWTILE + hw_t * 8 + 4];
            const float* wr  = &wsl[c * (NMID * 12) + mid_t * 12];
            const float4 wa  = *(const float4*)(wr);
            const float4 wb  = *(const float4*)(wr + 4);
            const float4 wc  = *(const float4*)(wr + 8);
            const float wj[10] = {wa.x, wa.y, wa.z, wa.w,
                                  wb.x, wb.y, wb.z, wb.w,
                                  wc.x, wc.y};
            #pragma unroll
            for (int j = 0; j < 10; ++j) {
                acc[j][0] = fmaf(wj[j], xv0.x, acc[j][0]);
                acc[j][1] = fmaf(wj[j], xv0.y, acc[j][1]);
                acc[j][2] = fmaf(wj[j], xv0.z, acc[j][2]);
                acc[j][3] = fmaf(wj[j], xv0.w, acc[j][3]);
                acc[j][4] = fmaf(wj[j], xv1.x, acc[j][4]);
                acc[j][5] = fmaf(wj[j], xv1.y, acc[j][5]);
                acc[j][6] = fmaf(wj[j], xv1.z, acc[j][6]);
                acc[j][7] = fmaf(wj[j], xv1.w, acc[j][7]);
            }
        }
        __syncthreads();
    }

    const int mid  = mid_t;
    const float bs = bvec[mid];
    // ---- score partial sum: this thread's 8 positions (+bias each) ----
    float sthr = 8.0f * bs;
    #pragma unroll
    for (int p = 0; p < 8; ++p) sthr += acc[0][p];
    sthr += __shfl_xor(sthr, 1);
    sthr += __shfl_xor(sthr, 2);
    sthr += __shfl_xor(sthr, 4);
    if (hw_t == 0) atomicAdd(&out[b * NMID + mid], sthr);

    // ---- softmax over the 9 kernel taps, per position ----
    float bk[9];
    #pragma unroll
    for (int j = 0; j < 9; ++j) bk[j] = bvec[NMID + mid * 9 + j];
    #pragma unroll
    for (int p = 0; p < 8; ++p) {
        float m = acc[1][p] + bk[0];
        #pragma unroll
        for (int j = 1; j < 9; ++j) m = fmaxf(m, acc[1 + j][p] + bk[j]);
        float s = 0.0f;
        #pragma unroll
        for (int j = 0; j < 9; ++j) {
            const float e = expf(acc[1 + j][p] + bk[j] - m);
            acc[1 + j][p] = e;
            s += e;
        }
        const float r = 1.0f / s;
        #pragma unroll
        for (int j = 0; j < 9; ++j) acc[1 + j][p] *= r;
    }
    float* ob = out + NORM_OFF + ((size_t)(b * NMID + mid) * 9) * HW + hw0 + hw_t * 8;
    #pragma unroll
    for (int j = 0; j < 9; ++j) {
        *(float4*)(ob + (size_t)j * HW) =
            make_float4(acc[1 + j][0], acc[1 + j][1], acc[1 + j][2], acc[1 + j][3]);
        *(float4*)(ob + (size_t)j * HW + 4) =
            make_float4(acc[1 + j][4], acc[1 + j][5], acc[1 + j][6], acc[1 + j][7]);
    }
}

// ---------------------------------------------------------------------------
// One block, 8 waves; wave b handles batch b. Sigmoid of means, stable top-k
// (descending value, tie -> lower index like jax.lax.top_k), mask, k, indices.
__global__ __launch_bounds__(512) void finalize_kernel(float* __restrict__ out, int k)
{
    const int tid  = threadIdx.x;
    const int b    = tid >> 6;
    const int lane = tid & 63;
    const float sum = out[b * NMID + lane];
    const float sv  = 1.0f / (1.0f + expf(-sum * (1.0f / 16384.0f)));
    float val      = sv;
    float selected = 0.0f;
    for (int t = 0; t < k; ++t) {
        float bvv = val;
        int   bi  = lane;
        #pragma unroll
        for (int off = 32; off >= 1; off >>= 1) {
            const float ov = __shfl_xor(bvv, off);
            const int   oi = __shfl_xor(bi, off);
            if (ov > bvv || (ov == bvv && oi < bi)) { bvv = ov; bi = oi; }
        }
        if (lane == bi) { val = -INFINITY; selected = 1.0f; }
        if (lane == 0) out[IDX_OFF + b * k + t] = (float)bi;
    }
    out[b * NMID + lane] = selected;            // overwrite accumulator with mask
    if (tid == 0) out[K_OFF] = (float)k;
}

// ---------------------------------------------------------------------------
extern "C" void kernel_launch(void* const* d_in, const int* in_sizes, int n_in,
                              void* d_out, int out_size, void* d_ws, size_t ws_size,
                              hipStream_t stream)
{
    const float* x    = (const float*)d_in[0];
    const float* Wm   = (const float*)d_in[1];
    const float* bvec = (const float*)d_in[2];
    float* out = (float*)d_out;

    // out_size = 512 (mask) + 75497472 (norm_kernels) + 1 (k) + 8*k (indices)
    const int k = (out_size - IDX_OFF) / 8;

    zero_mask_kernel<<<1, 512, 0, stream>>>(out);
    fused_main<<<8 * (HW / HWTILE), 512, 0, stream>>>(x, Wm, bvec, out);
    finalize_kernel<<<1, 512, 0, stream>>>(out, k);
}

// Round 2
// 712.674 us; speedup vs baseline: 1.4754x; 1.4754x over previous
//
#include <hip/hip_runtime.h>
#include <math.h>

constexpr int CIN      = 256;
constexpr int HW       = 16384;      // 128*128
constexpr int NMID     = 64;
constexpr int KCH      = 16;         // K-chunk staged per iteration
constexpr int HWTILE   = 64;         // spatial positions per block
constexpr int WROW     = NMID * 12;  // 768 floats per c-row in repacked W
constexpr int NORM_OFF = 512;        // mask (8*64) floats first
constexpr int K_OFF    = 75497984;   // 512 + 8*64*9*16384
constexpr int IDX_OFF  = 75497985;

// ---------------------------------------------------------------------------
// async global->LDS, 16B per lane. LDS dest must be wave-uniform base + lane*16
// (our destinations are lane-linear, which satisfies this).
__device__ __forceinline__ void gload_lds16(const float* gsrc, float* ldst) {
    __builtin_amdgcn_global_load_lds(
        (const __attribute__((address_space(1))) void*)gsrc,
        (__attribute__((address_space(3))) void*)ldst, 16, 0, 0);
}

// ---------------------------------------------------------------------------
// Repack W into d_ws: wp[c*768 + mid*12 + j] = W[o][c], o = mid (j=0) or
// 64 + mid*9 + (j-1) (j=1..9). Pad j=10,11 with zeros. 768 blocks x 256 thr.
__global__ __launch_bounds__(256) void repack_w(const float* __restrict__ Wm,
                                                float* __restrict__ wp)
{
    const int i   = blockIdx.x * 256 + threadIdx.x;   // over 256*768
    const int c   = i / WROW;
    const int r   = i - c * WROW;
    const int mid = r / 12;
    const int j   = r - mid * 12;
    float v = 0.0f;
    if (j < 10) {
        const int o = (j == 0) ? mid : (NMID + mid * 9 + (j - 1));
        v = Wm[(size_t)o * CIN + c];
    }
    wp[i] = v;
}

// ---------------------------------------------------------------------------
// Zero the mask region of d_out; it doubles as the score-sum accumulator.
__global__ __launch_bounds__(512) void zero_mask_kernel(float* __restrict__ out) {
    out[threadIdx.x] = 0.0f;
}

// ---------------------------------------------------------------------------
// Fused GEMM (640x256 @ 256xHW) + per-position 9-tap softmax + score sums.
// Block: 512 threads, 64 positions x all 64 mids of one batch (x read once).
// Thread (mid_t = tid>>3, hw_t = tid&7): 10 outputs x 8 positions = 80 accs.
__global__ __launch_bounds__(512) void fused_main(const float* __restrict__ x,
                                                  const float* __restrict__ wp,
                                                  const float* __restrict__ bvec,
                                                  float* __restrict__ out)
{
    __shared__ float xs[KCH * HWTILE];   // 4 KB,  [c][hw]
    __shared__ float wsl[KCH * WROW];    // 48 KB, [c][mid*12 + j] (j<10 used)
    const int tid    = threadIdx.x;
    const int wave   = tid >> 6;
    const int lane   = tid & 63;
    const int bid    = blockIdx.x;
    const int hw_blk = bid & 255;
    const int b      = bid >> 8;
    const int hw0    = hw_blk * HWTILE;
    const int mid_t  = tid >> 3;
    const int hw_t   = tid & 7;

    float acc[10][8];
    #pragma unroll
    for (int j = 0; j < 10; ++j)
        #pragma unroll
        for (int p = 0; p < 8; ++p) acc[j][p] = 0.0f;

    const float* xb = x + (size_t)b * CIN * HW + hw0;

    // x-stage addressing (constant across chunks except c0):
    // element-16 index e = wave*64+lane for wave<4; row = e>>4, col = e&15.
    const int xe   = wave * 64 + lane;
    const int xrow = xe >> 4;
    const int xcol = xe & 15;

    #pragma unroll 1
    for (int ch = 0; ch < CIN / KCH; ++ch) {
        const int c0 = ch * KCH;
        // ---- stage x chunk: 16 rows x 64 floats, 4 waves x 1KB ----
        if (wave < 4)
            gload_lds16(xb + (size_t)(c0 + xrow) * HW + xcol * 4, &xs[xe * 4]);
        // ---- stage W chunk: contiguous 12288 floats from repacked wp ----
        const float* wsrc = wp + (size_t)c0 * WROW;
        #pragma unroll
        for (int r6 = 0; r6 < 6; ++r6) {
            const int e = r6 * 512 + tid;
            gload_lds16(wsrc + e * 4, &wsl[e * 4]);
        }
        __syncthreads();
        // ---- FMA inner loop: per c: 5 ds_read_b128 + 80 v_fma_f32 ----
        #pragma unroll 4
        for (int c = 0; c < KCH; ++c) {
            const float4 xv0 = *(const float4*)&xs[c * HWTILE + hw_t * 8];
            const float4 xv1 = *(const float4*)&xs[c * HWTILE + hw_t * 8 + 4];
            const float* wr  = &wsl[c * WROW + mid_t * 12];
            const float4 wa  = *(const float4*)(wr);
            const float4 wb  = *(const float4*)(wr + 4);
            const float4 wc  = *(const float4*)(wr + 8);
            const float wj[10] = {wa.x, wa.y, wa.z, wa.w,
                                  wb.x, wb.y, wb.z, wb.w,
                                  wc.x, wc.y};
            #pragma unroll
            for (int j = 0; j < 10; ++j) {
                acc[j][0] = fmaf(wj[j], xv0.x, acc[j][0]);
                acc[j][1] = fmaf(wj[j], xv0.y, acc[j][1]);
                acc[j][2] = fmaf(wj[j], xv0.z, acc[j][2]);
                acc[j][3] = fmaf(wj[j], xv0.w, acc[j][3]);
                acc[j][4] = fmaf(wj[j], xv1.x, acc[j][4]);
                acc[j][5] = fmaf(wj[j], xv1.y, acc[j][5]);
                acc[j][6] = fmaf(wj[j], xv1.z, acc[j][6]);
                acc[j][7] = fmaf(wj[j], xv1.w, acc[j][7]);
            }
        }
        __syncthreads();
    }

    const int mid  = mid_t;
    const float bs = bvec[mid];
    // ---- score partial sum: this thread's 8 positions (+bias each) ----
    float sthr = 8.0f * bs;
    #pragma unroll
    for (int p = 0; p < 8; ++p) sthr += acc[0][p];
    sthr += __shfl_xor(sthr, 1);
    sthr += __shfl_xor(sthr, 2);
    sthr += __shfl_xor(sthr, 4);
    if (hw_t == 0) atomicAdd(&out[b * NMID + mid], sthr);

    // ---- softmax over the 9 kernel taps, per position ----
    float bk[9];
    #pragma unroll
    for (int j = 0; j < 9; ++j) bk[j] = bvec[NMID + mid * 9 + j];
    #pragma unroll
    for (int p = 0; p < 8; ++p) {
        float m = acc[1][p] + bk[0];
        #pragma unroll
        for (int j = 1; j < 9; ++j) m = fmaxf(m, acc[1 + j][p] + bk[j]);
        float s = 0.0f;
        #pragma unroll
        for (int j = 0; j < 9; ++j) {
            const float e = __expf(acc[1 + j][p] + bk[j] - m);
            acc[1 + j][p] = e;
            s += e;
        }
        const float r = 1.0f / s;
        #pragma unroll
        for (int j = 0; j < 9; ++j) acc[1 + j][p] *= r;
    }
    float* ob = out + NORM_OFF + ((size_t)(b * NMID + mid) * 9) * HW + hw0 + hw_t * 8;
    #pragma unroll
    for (int j = 0; j < 9; ++j) {
        *(float4*)(ob + (size_t)j * HW) =
            make_float4(acc[1 + j][0], acc[1 + j][1], acc[1 + j][2], acc[1 + j][3]);
        *(float4*)(ob + (size_t)j * HW + 4) =
            make_float4(acc[1 + j][4], acc[1 + j][5], acc[1 + j][6], acc[1 + j][7]);
    }
}

// ---------------------------------------------------------------------------
// One block, 8 waves; wave b handles batch b. Sigmoid of means, stable top-k
// (descending value, tie -> lower index like jax.lax.top_k), mask, k, indices.
__global__ __launch_bounds__(512) void finalize_kernel(float* __restrict__ out, int k)
{
    const int tid  = threadIdx.x;
    const int b    = tid >> 6;
    const int lane = tid & 63;
    const float sum = out[b * NMID + lane];
    const float sv  = 1.0f / (1.0f + __expf(-sum * (1.0f / 16384.0f)));
    float val      = sv;
    float selected = 0.0f;
    for (int t = 0; t < k; ++t) {
        float bvv = val;
        int   bi  = lane;
        #pragma unroll
        for (int off = 32; off >= 1; off >>= 1) {
            const float ov = __shfl_xor(bvv, off);
            const int   oi = __shfl_xor(bi, off);
            if (ov > bvv || (ov == bvv && oi < bi)) { bvv = ov; bi = oi; }
        }
        if (lane == bi) { val = -INFINITY; selected = 1.0f; }
        if (lane == 0) out[IDX_OFF + b * k + t] = (float)bi;
    }
    out[b * NMID + lane] = selected;            // overwrite accumulator with mask
    if (tid == 0) out[K_OFF] = (float)k;
}

// ---------------------------------------------------------------------------
extern "C" void kernel_launch(void* const* d_in, const int* in_sizes, int n_in,
                              void* d_out, int out_size, void* d_ws, size_t ws_size,
                              hipStream_t stream)
{
    const float* x    = (const float*)d_in[0];
    const float* Wm   = (const float*)d_in[1];
    const float* bvec = (const float*)d_in[2];
    float* out = (float*)d_out;
    float* wp  = (float*)d_ws;          // 256*768 floats = 768 KB repacked W

    // out_size = 512 (mask) + 75497472 (norm_kernels) + 1 (k) + 8*k (indices)
    const int k = (out_size - IDX_OFF) / 8;

    repack_w<<<CIN * WROW / 256, 256, 0, stream>>>(Wm, wp);
    zero_mask_kernel<<<1, 512, 0, stream>>>(out);
    fused_main<<<8 * (HW / HWTILE), 512, 0, stream>>>(x, wp, bvec, out);
    finalize_kernel<<<1, 512, 0, stream>>>(out, k);
}

// Round 3
// 390.972 us; speedup vs baseline: 2.6894x; 1.8228x over previous
//
#include <hip/hip_runtime.h>
#include <math.h>

constexpr int CIN      = 256;
constexpr int HW       = 16384;       // 128*128
constexpr int NMID     = 64;
constexpr int HWTILE   = 128;         // spatial positions per block
constexpr int GROUPS   = 8;           // 8 groups x 8 mids (80 rows) each
constexpr int TILE_B   = 8192;        // padded A-tile image (80 rows x 80B)
constexpr int NORM_OFF = 512;         // mask (8*64) floats first
constexpr int K_OFF    = 75497984;    // 512 + 8*64*9*16384
constexpr int IDX_OFF  = 75497985;

typedef __attribute__((ext_vector_type(8))) short bf16x8;   // 8 bf16 = 4 VGPR
typedef __attribute__((ext_vector_type(4))) float f32x4;

__device__ __forceinline__ unsigned bf16_rne(float f) {
    unsigned u = __float_as_uint(f);
    return (u + 0x7fffu + ((u >> 16) & 1u)) >> 16;          // bf16 bits, RNE
}

__device__ __forceinline__ void gload_lds16(const void* gsrc, void* ldst) {
    __builtin_amdgcn_global_load_lds(
        (const __attribute__((address_space(1))) void*)gsrc,
        (__attribute__((address_space(3))) void*)ldst, 16, 0, 0);
}

// ---------------------------------------------------------------------------
// Repack W into MFMA A-fragment byte image in d_ws, split bf16 hi/lo.
// Row order r = mid*10 + j (j=0 score, 1..9 taps). Image tile (g,k,part):
// 80 rows x 32 c (bf16), row stride 80B, tile padded to 8192B.
__global__ __launch_bounds__(256) void prep_w(const float* __restrict__ Wm,
                                              char* __restrict__ ws)
{
    const int r   = blockIdx.x;       // 0..639
    const int c   = threadIdx.x;      // 0..255
    const int mid = r / 10, j = r - mid * 10;
    const int o   = (j == 0) ? mid : (NMID + mid * 9 + (j - 1));
    const float w = Wm[(size_t)o * CIN + c];
    const unsigned hi = bf16_rne(w);
    const float    fl = w - __uint_as_float(hi << 16);
    const unsigned lo = bf16_rne(fl);
    const int g = r / 80, lr = r - g * 80;
    const int k = c >> 5, cc = c & 31;
    char* base = ws + (size_t)((g * 8 + k) * 2) * TILE_B + lr * 80 + cc * 2;
    *(unsigned short*)(base)          = (unsigned short)hi;
    *(unsigned short*)(base + TILE_B) = (unsigned short)lo;
}

// ---------------------------------------------------------------------------
__global__ __launch_bounds__(512) void zero_mask_kernel(float* __restrict__ out) {
    out[threadIdx.x] = 0.0f;
}

// ---------------------------------------------------------------------------
// Split-bf16 MFMA GEMM (640x256 @ 256x128-tile) + 9-tap softmax + score sums.
// 8 waves; wave w owns hw columns [hw0+16w, hw0+16w+16). B-frags (x) resident
// in registers for full K; A (W) double-buffered in LDS via global_load_lds.
__global__ __launch_bounds__(512, 4) void fused_main(const float* __restrict__ x,
                                                     const char* __restrict__ wimg,
                                                     const float* __restrict__ bvec,
                                                     float* __restrict__ out)
{
    __shared__ __align__(16) char atile[2][2][TILE_B];   // 32 KB [buf][hi/lo]
    __shared__ float raw[80 * HWTILE];                   // 40 KB
    __shared__ float bsh[640];                           // 2.5 KB biases

    const int tid  = threadIdx.x;
    const int wave = tid >> 6, lane = tid & 63;
    const int q    = lane >> 4, m = lane & 15;
    const int b    = blockIdx.x >> 7;
    const int hw0  = (blockIdx.x & 127) * HWTILE;

    for (int i = tid; i < 640; i += 512) bsh[i] = bvec[i];

    // ---- build B fragments: x[c][hw], lane holds 8 consecutive c ----
    const float* xcol = x + (size_t)b * CIN * HW + hw0 + wave * 16 + m;
    bf16x8 Bhi[8], Blo[8];
    #pragma unroll
    for (int k = 0; k < 8; ++k) {
        float f[8];
        #pragma unroll
        for (int i = 0; i < 8; ++i)
            f[i] = xcol[(size_t)(k * 32 + q * 8 + i) * HW];
        union { unsigned u[4]; bf16x8 v; } uh, ul;
        #pragma unroll
        for (int jj = 0; jj < 4; ++jj) {
            const unsigned h0 = bf16_rne(f[2*jj]), h1 = bf16_rne(f[2*jj+1]);
            const float    r0 = f[2*jj]   - __uint_as_float(h0 << 16);
            const float    r1 = f[2*jj+1] - __uint_as_float(h1 << 16);
            uh.u[jj] = h0 | (h1 << 16);
            ul.u[jj] = bf16_rne(r0) | (bf16_rne(r1) << 16);
        }
        Bhi[k] = uh.v; Blo[k] = ul.v;
    }
    __syncthreads();   // bsh staged; all loads drained

    #pragma unroll 1
    for (int g = 0; g < GROUPS; ++g) {
        f32x4 acc[5];
        #pragma unroll
        for (int ot = 0; ot < 5; ++ot) acc[ot] = (f32x4){0.f, 0.f, 0.f, 0.f};

        // prologue: stage k=0 into buf0 (2 x 8KB, 1 gload_lds/thread/part)
        {
            const char* src = wimg + (size_t)((g * 8) * 2) * TILE_B + tid * 16;
            gload_lds16(src,          &atile[0][0][tid * 16]);
            gload_lds16(src + TILE_B, &atile[0][1][tid * 16]);
        }
        #pragma unroll
        for (int k = 0; k < 8; ++k) {
            const int cur = k & 1;
            if (k < 7) {
                const char* src = wimg + (size_t)((g * 8 + k + 1) * 2) * TILE_B + tid * 16;
                gload_lds16(src,          &atile[cur ^ 1][0][tid * 16]);
                gload_lds16(src + TILE_B, &atile[cur ^ 1][1][tid * 16]);
                asm volatile("s_waitcnt vmcnt(2)" ::: "memory");
            } else {
                asm volatile("s_waitcnt vmcnt(0)" ::: "memory");
            }
            __builtin_amdgcn_s_barrier();

            const char* ahi = &atile[cur][0][m * 80 + q * 16];
            const char* alo = &atile[cur][1][m * 80 + q * 16];
            const bf16x8 bh = Bhi[k], bl = Blo[k];
            #pragma unroll
            for (int ot = 0; ot < 5; ++ot) {
                const bf16x8 Ah = *(const bf16x8*)(ahi + ot * 1280);
                const bf16x8 Al = *(const bf16x8*)(alo + ot * 1280);
                acc[ot] = __builtin_amdgcn_mfma_f32_16x16x32_bf16(Ah, bh, acc[ot], 0, 0, 0);
                acc[ot] = __builtin_amdgcn_mfma_f32_16x16x32_bf16(Ah, bl, acc[ot], 0, 0, 0);
                acc[ot] = __builtin_amdgcn_mfma_f32_16x16x32_bf16(Al, bh, acc[ot], 0, 0, 0);
            }
            asm volatile("s_waitcnt lgkmcnt(0)" ::: "memory");
            __builtin_amdgcn_s_barrier();
        }

        // ---- acc -> raw LDS (D: col=lane&15, row=(lane>>4)*4+reg) ----
        #pragma unroll
        for (int ot = 0; ot < 5; ++ot)
            #pragma unroll
            for (int r = 0; r < 4; ++r)
                raw[(ot * 16 + q * 4 + r) * HWTILE + wave * 16 + m] = acc[ot][r];
        asm volatile("s_waitcnt lgkmcnt(0)" ::: "memory");
        __builtin_amdgcn_s_barrier();

        // ---- epilogue: 2 items/thread (mid, hw); wave-uniform mid ----
        #pragma unroll
        for (int half = 0; half < 2; ++half) {
            const int item  = tid + half * 512;
            const int mid_l = item >> 7;            // 0..7
            const int hw    = item & 127;
            const int gmid  = g * 8 + mid_l;
            // score row: reduce over this wave's 64 hw, one atomic
            float s = raw[(mid_l * 10) * HWTILE + hw];
            #pragma unroll
            for (int off = 32; off >= 1; off >>= 1) s += __shfl_xor(s, off);
            if (lane == 0) atomicAdd(&out[b * NMID + gmid], s);
            // 9-tap softmax
            float p[9];
            #pragma unroll
            for (int j = 0; j < 9; ++j)
                p[j] = raw[(mid_l * 10 + 1 + j) * HWTILE + hw] + bsh[NMID + gmid * 9 + j];
            float mx = p[0];
            #pragma unroll
            for (int j = 1; j < 9; ++j) mx = fmaxf(mx, p[j]);
            float ssum = 0.f;
            #pragma unroll
            for (int j = 0; j < 9; ++j) { p[j] = __expf(p[j] - mx); ssum += p[j]; }
            const float rs = 1.0f / ssum;
            float* ob = out + NORM_OFF + ((size_t)((b * NMID + gmid) * 9)) * HW + hw0 + hw;
            #pragma unroll
            for (int j = 0; j < 9; ++j) ob[(size_t)j * HW] = p[j] * rs;
        }
        // next group's raw writes are behind 16 barriers -> no barrier needed
    }
}

// ---------------------------------------------------------------------------
// One block, 8 waves; wave b handles batch b. Sigmoid of means (+score bias),
// stable top-k (desc value, tie -> lower index), mask, k, indices.
__global__ __launch_bounds__(512) void finalize_kernel(float* __restrict__ out,
                                                       const float* __restrict__ bvec,
                                                       int k)
{
    const int tid  = threadIdx.x;
    const int b    = tid >> 6;
    const int lane = tid & 63;
    const float sum = out[b * NMID + lane];
    const float sv  = 1.0f / (1.0f + __expf(-(sum * (1.0f / 16384.0f) + bvec[lane])));
    float val      = sv;
    float selected = 0.0f;
    for (int t = 0; t < k; ++t) {
        float bvv = val;
        int   bi  = lane;
        #pragma unroll
        for (int off = 32; off >= 1; off >>= 1) {
            const float ov = __shfl_xor(bvv, off);
            const int   oi = __shfl_xor(bi, off);
            if (ov > bvv || (ov == bvv && oi < bi)) { bvv = ov; bi = oi; }
        }
        if (lane == bi) { val = -INFINITY; selected = 1.0f; }
        if (lane == 0) out[IDX_OFF + b * k + t] = (float)bi;
    }
    out[b * NMID + lane] = selected;            // overwrite sums with mask
    if (tid == 0) out[K_OFF] = (float)k;
}

// ---------------------------------------------------------------------------
extern "C" void kernel_launch(void* const* d_in, const int* in_sizes, int n_in,
                              void* d_out, int out_size, void* d_ws, size_t ws_size,
                              hipStream_t stream)
{
    const float* x    = (const float*)d_in[0];
    const float* Wm   = (const float*)d_in[1];
    const float* bvec = (const float*)d_in[2];
    float* out = (float*)d_out;
    char*  ws  = (char*)d_ws;           // 8*8*2*8192 = 1 MB W fragment image

    // out_size = 512 (mask) + 75497472 (norm_kernels) + 1 (k) + 8*k (indices)
    const int k = (out_size - IDX_OFF) / 8;

    prep_w<<<640, 256, 0, stream>>>(Wm, ws);
    zero_mask_kernel<<<1, 512, 0, stream>>>(out);
    fused_main<<<8 * (HW / HWTILE), 512, 0, stream>>>(x, ws, bvec, out);
    finalize_kernel<<<1, 512, 0, stream>>>(out, bvec, k);
}

// Round 4
// 234.621 us; speedup vs baseline: 4.4816x; 1.6664x over previous
//
#include <hip/hip_runtime.h>
#include <math.h>

constexpr int CIN      = 256;
constexpr int HW       = 16384;       // 128*128
constexpr int NMID     = 64;
constexpr int HWTILE   = 128;         // spatial positions per block (4 waves x 32)
constexpr int TILE_B   = 8192;        // padded A-tile image (80 rows x 80B)
constexpr int NORM_OFF = 512;         // mask (8*64) floats first
constexpr int K_OFF    = 75497984;    // 512 + 8*64*9*16384
constexpr int IDX_OFF  = 75497985;

typedef __attribute__((ext_vector_type(8))) short bf16x8;   // 8 bf16 = 4 VGPR
typedef __attribute__((ext_vector_type(4))) float f32x4;

__device__ __forceinline__ unsigned bf16_rne(float f) {
    unsigned u = __float_as_uint(f);
    return (u + 0x7fffu + ((u >> 16) & 1u)) >> 16;          // bf16 bits, RNE
}

__device__ __forceinline__ void gload_lds16(const void* gsrc, void* ldst) {
    __builtin_amdgcn_global_load_lds(
        (const __attribute__((address_space(1))) void*)gsrc,
        (__attribute__((address_space(3))) void*)ldst, 16, 0, 0);
}

// ---------------------------------------------------------------------------
// Repack W into MFMA A-fragment image, split bf16 hi/lo, with a row permutation
// chosen so each mid's 10 rows (score + 9 taps) land in ONE lane's D-fragments:
// D row-in-block = q*4+reg  =>  position p = (idx/4)*16 + q*4 + idx%4, where
// q = (mid&7)>>1, idx = (mid&1)*10 + j.  Tile (g*8+kc, part): 80 rows x 32 c.
__global__ __launch_bounds__(256) void prep_w(const float* __restrict__ Wm,
                                              char* __restrict__ ws)
{
    const int o = blockIdx.x;         // original W row 0..639
    const int c = threadIdx.x;        // 0..255
    int mid, j;
    if (o < NMID) { mid = o; j = 0; }
    else          { mid = (o - NMID) / 9; j = 1 + (o - NMID) % 9; }
    const int g  = mid >> 3, ml = mid & 7, q = ml >> 1, mi = ml & 1;
    const int idx = mi * 10 + j;
    const int p   = (idx >> 2) * 16 + q * 4 + (idx & 3);    // tile row 0..79
    const float w = Wm[(size_t)o * CIN + c];
    const unsigned hi = bf16_rne(w);
    const float    fl = w - __uint_as_float(hi << 16);
    const unsigned lo = bf16_rne(fl);
    const int kc = c >> 5, cc = c & 31;
    char* base = ws + (size_t)((g * 8 + kc) * 2) * TILE_B + p * 80 + cc * 2;
    *(unsigned short*)(base)          = (unsigned short)hi;
    *(unsigned short*)(base + TILE_B) = (unsigned short)lo;
}

// ---------------------------------------------------------------------------
__global__ __launch_bounds__(512) void zero_mask_kernel(float* __restrict__ out) {
    out[threadIdx.x] = 0.0f;
}

// ---------------------------------------------------------------------------
// Split-bf16 MFMA GEMM (640x256 @ 256x128-tile) + lane-local softmax epilogue.
// 4 waves; wave w owns hw [hw0+32w, hw0+32w+32) as two 16-col tiles (nh=2).
// B-frags (x) resident in registers for full K; A double-buffered in LDS.
__global__ __launch_bounds__(256, 2) void fused_main(const float* __restrict__ x,
                                                     const char* __restrict__ wimg,
                                                     const float* __restrict__ bvec,
                                                     float* __restrict__ out)
{
    __shared__ __align__(16) char atile[2][2][TILE_B];   // 32 KB [buf][hi/lo]
    __shared__ float bsh[640];

    const int tid  = threadIdx.x;
    const int wave = tid >> 6, lane = tid & 63;
    const int q    = lane >> 4, m = lane & 15;
    const int b    = blockIdx.x >> 7;
    const int hw0  = (blockIdx.x & 127) * HWTILE;

    for (int i = tid; i < 640; i += 256) bsh[i] = bvec[i];

    // ---- B fragments: x[c][hw], lane holds 8 consecutive c; split hi/lo ----
    bf16x8 Bhi[2][8], Blo[2][8];
    const float* xb = x + (size_t)b * CIN * HW + hw0 + wave * 32 + m;
    #pragma unroll
    for (int t = 0; t < 2; ++t)
        #pragma unroll
        for (int kc = 0; kc < 8; ++kc) {
            float f[8];
            #pragma unroll
            for (int i = 0; i < 8; ++i)
                f[i] = xb[t * 16 + (size_t)(kc * 32 + q * 8 + i) * HW];
            union { unsigned u[4]; bf16x8 v; } uh, ul;
            #pragma unroll
            for (int jj = 0; jj < 4; ++jj) {
                const unsigned h0 = bf16_rne(f[2*jj]), h1 = bf16_rne(f[2*jj+1]);
                const float r0 = f[2*jj]   - __uint_as_float(h0 << 16);
                const float r1 = f[2*jj+1] - __uint_as_float(h1 << 16);
                uh.u[jj] = h0 | (h1 << 16);
                ul.u[jj] = bf16_rne(r0) | (bf16_rne(r1) << 16);
            }
            Bhi[t][kc] = uh.v; Blo[t][kc] = ul.v;
        }
    __syncthreads();

#define STAGE(tile, buf) do {                                                  \
    const char* _s = wimg + (size_t)((tile) * 2) * TILE_B;                     \
    gload_lds16(_s + tid * 16,                 &atile[buf][0][tid * 16]);      \
    gload_lds16(_s + 4096 + tid * 16,          &atile[buf][0][4096 + tid*16]); \
    gload_lds16(_s + TILE_B + tid * 16,        &atile[buf][1][tid * 16]);      \
    gload_lds16(_s + TILE_B + 4096 + tid * 16, &atile[buf][1][4096 + tid*16]); \
} while (0)

    STAGE(0, 0);
    #pragma unroll 1
    for (int g = 0; g < 8; ++g) {
        f32x4 acc[5][2];
        #pragma unroll
        for (int ot = 0; ot < 5; ++ot)
            #pragma unroll
            for (int t = 0; t < 2; ++t) acc[ot][t] = (f32x4){0.f, 0.f, 0.f, 0.f};

        #pragma unroll
        for (int kc = 0; kc < 8; ++kc) {
            const int cur = kc & 1;
            if (kc < 7)     STAGE(g * 8 + kc + 1, cur ^ 1);
            else if (g < 7) STAGE((g + 1) * 8,    cur ^ 1);   // prefetch next group
            if (g == 7 && kc == 7) asm volatile("s_waitcnt vmcnt(0)" ::: "memory");
            else                   asm volatile("s_waitcnt vmcnt(4)" ::: "memory");
            __builtin_amdgcn_s_barrier();

            const char* ahi = &atile[cur][0][m * 80 + q * 16];
            const char* alo = &atile[cur][1][m * 80 + q * 16];
            #pragma unroll
            for (int ot = 0; ot < 5; ++ot) {
                const bf16x8 Ah = *(const bf16x8*)(ahi + ot * 1280);
                const bf16x8 Al = *(const bf16x8*)(alo + ot * 1280);
                #pragma unroll
                for (int t = 0; t < 2; ++t) {
                    acc[ot][t] = __builtin_amdgcn_mfma_f32_16x16x32_bf16(Ah, Bhi[t][kc], acc[ot][t], 0, 0, 0);
                    acc[ot][t] = __builtin_amdgcn_mfma_f32_16x16x32_bf16(Ah, Blo[t][kc], acc[ot][t], 0, 0, 0);
                    acc[ot][t] = __builtin_amdgcn_mfma_f32_16x16x32_bf16(Al, Bhi[t][kc], acc[ot][t], 0, 0, 0);
                }
            }
            asm volatile("s_waitcnt lgkmcnt(0)" ::: "memory");
            __builtin_amdgcn_s_barrier();
        }

        // ---- lane-local epilogue: this lane owns mids q*2, q*2+1 of group g,
        //      at hw = hw0 + wave*32 + t*16 + m.  raw(idx) = acc[idx>>2][t][idx&3].
        #pragma unroll
        for (int mi = 0; mi < 2; ++mi) {
            const int gmid = g * 8 + q * 2 + mi;
            const int i0 = mi * 10;
            // score: sum over this lane's 2 hw + 16-lane quarter reduce
            float s = acc[i0 >> 2][0][i0 & 3] + acc[i0 >> 2][1][i0 & 3];
            s += __shfl_xor(s, 1); s += __shfl_xor(s, 2);
            s += __shfl_xor(s, 4); s += __shfl_xor(s, 8);
            if (m == 0) atomicAdd(&out[b * NMID + gmid], s);
            float bj[9];
            #pragma unroll
            for (int jj = 0; jj < 9; ++jj) bj[jj] = bsh[NMID + gmid * 9 + jj];
            #pragma unroll
            for (int t = 0; t < 2; ++t) {
                float p[9];
                #pragma unroll
                for (int jj = 0; jj < 9; ++jj) {
                    const int idx = i0 + 1 + jj;
                    p[jj] = acc[idx >> 2][t][idx & 3] + bj[jj];
                }
                float mx = p[0];
                #pragma unroll
                for (int jj = 1; jj < 9; ++jj) mx = fmaxf(mx, p[jj]);
                float ss = 0.f;
                #pragma unroll
                for (int jj = 0; jj < 9; ++jj) { p[jj] = __expf(p[jj] - mx); ss += p[jj]; }
                const float rs = 1.0f / ss;
                float* ob = out + NORM_OFF
                          + ((size_t)((b * NMID + gmid) * 9)) * HW
                          + hw0 + wave * 32 + t * 16 + m;
                #pragma unroll
                for (int jj = 0; jj < 9; ++jj)
                    ob[(size_t)jj * HW] = p[jj] * rs;
            }
        }
    }
#undef STAGE
}

// ---------------------------------------------------------------------------
// One block, 8 waves; wave b handles batch b. Sigmoid of means (+score bias),
// stable top-k (desc value, tie -> lower index), mask, k, indices.
__global__ __launch_bounds__(512) void finalize_kernel(float* __restrict__ out,
                                                       const float* __restrict__ bvec,
                                                       int k)
{
    const int tid  = threadIdx.x;
    const int b    = tid >> 6;
    const int lane = tid & 63;
    const float sum = out[b * NMID + lane];
    const float sv  = 1.0f / (1.0f + __expf(-(sum * (1.0f / 16384.0f) + bvec[lane])));
    float val      = sv;
    float selected = 0.0f;
    for (int t = 0; t < k; ++t) {
        float bvv = val;
        int   bi  = lane;
        #pragma unroll
        for (int off = 32; off >= 1; off >>= 1) {
            const float ov = __shfl_xor(bvv, off);
            const int   oi = __shfl_xor(bi, off);
            if (ov > bvv || (ov == bvv && oi < bi)) { bvv = ov; bi = oi; }
        }
        if (lane == bi) { val = -INFINITY; selected = 1.0f; }
        if (lane == 0) out[IDX_OFF + b * k + t] = (float)bi;
    }
    out[b * NMID + lane] = selected;            // overwrite sums with mask
    if (tid == 0) out[K_OFF] = (float)k;
}

// ---------------------------------------------------------------------------
extern "C" void kernel_launch(void* const* d_in, const int* in_sizes, int n_in,
                              void* d_out, int out_size, void* d_ws, size_t ws_size,
                              hipStream_t stream)
{
    const float* x    = (const float*)d_in[0];
    const float* Wm   = (const float*)d_in[1];
    const float* bvec = (const float*)d_in[2];
    float* out = (float*)d_out;
    char*  ws  = (char*)d_ws;           // 64 tiles x 2 parts x 8192 B = 1 MB

    // out_size = 512 (mask) + 75497472 (norm_kernels) + 1 (k) + 8*k (indices)
    const int k = (out_size - IDX_OFF) / 8;

    prep_w<<<640, 256, 0, stream>>>(Wm, ws);
    zero_mask_kernel<<<1, 512, 0, stream>>>(out);
    fused_main<<<8 * (HW / HWTILE), 256, 0, stream>>>(x, ws, bvec, out);
    finalize_kernel<<<1, 512, 0, stream>>>(out, bvec, k);
}